// Round 1
// baseline (2426.756 us; speedup 1.0000x reference)
//
#include <hip/hip_runtime.h>
#include <hip/hip_bf16.h>
#include <cstdint>

#define B_ 4096
#define H_ 256
#define G_ 1024   // 4*H
#define T_ 64
#define L_ 5

typedef __hip_bfloat16 bf16;
typedef __bf16 bf16x8 __attribute__((ext_vector_type(8)));
typedef float f32x4 __attribute__((ext_vector_type(4)));

// ---- workspace layout (bytes) ----
#define OFF_WCOMB   0ull            // [5][1024][512] bf16 (l=0: cols0-255=w_hh0)
#define OFF_WIH0R   5242880ull      // [1024][256] bf16 reordered w_ih[0]
#define OFF_LWB     5767168ull      // [256][128] bf16 linear_w
#define OFF_XB      5832704ull      // [4096][128] bf16 x
#define OFF_OBW     6881280ull      // [96][256] bf16 out_w padded
#define OFF_BIAS    6930432ull      // [5][1024] f32 (slot0 = bih0+bhh0 reordered)
#define OFF_XP      6950912ull      // [4096][256] bf16
#define OFF_GX0     9048064ull      // [4096][1024] f32
#define OFF_H0      25825280ull     // h parity0: [4][4096][256] bf16
#define OFF_H1      34213888ull     // h parity1 (zeroed)
#define OFF_C1      42602496ull     // c parity1: [5][4096][256] f32 (zeroed)
#define OFF_YS      63574016ull     // [65][4096][256] bf16, slot0 zeroed
#define OFF_C0      199888896ull    // c parity0
#define TOTAL_WS    220860416ull
#define ZERO_BYTES  31457280ull     // H1 + C1 + YS slot0 (contiguous)
#define SLOT_H      2097152ull
#define SLOT_C      4194304ull

__device__ __forceinline__ bf16* h_ptr(char* ws, int l, int p) {
  return (bf16*)(ws + (p ? OFF_H1 : OFF_H0) + (size_t)l * SLOT_H);
}
__device__ __forceinline__ float* c_ptr(char* ws, int l, int p) {
  return (float*)(ws + (p ? OFF_C1 : OFF_C0) + (size_t)l * SLOT_C);
}
__device__ __forceinline__ bf16* ys_ptr(char* ws, int s) {
  return (bf16*)(ws + OFF_YS + (size_t)s * SLOT_H);
}

__device__ __forceinline__ float frcp(float x) { return __builtin_amdgcn_rcpf(x); }
__device__ __forceinline__ float fsig(float x) { return frcp(1.0f + __expf(-x)); }
__device__ __forceinline__ float ftanh(float x) { return 1.0f - 2.0f * frcp(1.0f + __expf(2.0f * x)); }

__device__ __forceinline__ void gload16(const void* g, void* l) {
  __builtin_amdgcn_global_load_lds((const __attribute__((address_space(1))) void*)g,
                                   (__attribute__((address_space(3))) void*)l, 16, 0, 0);
}

// stage one 128x64 bf16 tile into LDS (linear [128][64]) with 16B XOR source-swizzle
__device__ __forceinline__ void stage_tile(char* dst, const bf16* src, long stride, int koff,
                                           int wv, int lane) {
#pragma unroll
  for (int i = 0; i < 4; ++i) {
    int r = 32 * wv + 8 * i + (lane >> 3);
    int cb = ((lane & 7) << 4) ^ ((r & 7) << 4);   // swizzled source byte col in [0,128)
    const bf16* g = src + (long)r * stride + koff + (cb >> 1);
    char* ld = dst + (32 * wv + 8 * i) * 128;       // wave-uniform base; +lane*16 implicit
    gload16(g, ld);
  }
}

// OUTMODE: 0 = f32 store, 1 = bf16 store, 2 = LSTM cell update
template <int OUTMODE>
__device__ void gemm_core(const bf16* __restrict__ A1, int lda1,
                          const bf16* __restrict__ A2,            // stride 256, k>=256
                          const bf16* __restrict__ W, int ldw, int K,
                          const float* __restrict__ bias,         // row bias [N] (may be null)
                          const float* __restrict__ acc2d,        // [M][1024] f32 acc-init (or null)
                          float* __restrict__ outF, bf16* __restrict__ outB, int ldo,
                          const float* __restrict__ cIn, float* __restrict__ cOut,
                          bf16* __restrict__ hOut,
                          int mtile, int ntile, char* smem) {
  const int tid = threadIdx.x;
  const int lane = tid & 63, wv = tid >> 6;
  const int wrow = wv >> 1, wcol = wv & 1;
  const int row0 = mtile * 128;
  const int n0 = ntile * 128;

  char* As[2] = { smem,          smem + 16384 };
  char* Bs[2] = { smem + 32768,  smem + 49152 };

  f32x4 acc[4][4];
  if (acc2d) {
#pragma unroll
    for (int m = 0; m < 4; m++)
#pragma unroll
      for (int n = 0; n < 4; n++)
#pragma unroll
        for (int r = 0; r < 4; r++) {
          int row = row0 + wrow * 64 + 16 * m + ((lane >> 4) << 2) + r;
          int col = n0 + wcol * 64 + 16 * n + (lane & 15);
          acc[m][n][r] = acc2d[(long)row * G_ + col];
        }
  } else {
#pragma unroll
    for (int n = 0; n < 4; n++) {
      int col = n0 + wcol * 64 + 16 * n + (lane & 15);
      float bv = bias ? bias[col] : 0.0f;
#pragma unroll
      for (int m = 0; m < 4; m++)
#pragma unroll
        for (int r = 0; r < 4; r++) acc[m][n][r] = bv;
    }
  }

  const int nkb = K >> 6;
  // prologue: stage kb=0
  {
    const bf16* s = A1 + (long)row0 * lda1;
    stage_tile(As[0], s, lda1, 0, wv, lane);
    stage_tile(Bs[0], W + (long)n0 * ldw, ldw, 0, wv, lane);
  }
  for (int kb = 0; kb < nkb; ++kb) {
    __syncthreads();   // drains vmcnt: staged buf ready; all waves done with prev compute
    if (kb + 1 < nkb) {
      int k2 = kb + 1, b = k2 & 1;
      if (k2 < 4) stage_tile(As[b], A1 + (long)row0 * lda1, lda1, k2 * 64, wv, lane);
      else        stage_tile(As[b], A2 + (long)row0 * 256,  256,  k2 * 64 - 256, wv, lane);
      stage_tile(Bs[b], W + (long)n0 * ldw, ldw, k2 * 64, wv, lane);
    }
    char* Ab = As[kb & 1]; char* Bb = Bs[kb & 1];
#pragma unroll
    for (int ks = 0; ks < 2; ++ks) {
      bf16x8 af[4], bfr[4];
#pragma unroll
      for (int m = 0; m < 4; m++) {
        int r = wrow * 64 + 16 * m + (lane & 15);
        int cb = (ks * 64 + ((lane >> 4) << 4)) ^ ((r & 7) << 4);
        af[m] = *(const bf16x8*)(Ab + r * 128 + cb);
      }
#pragma unroll
      for (int n = 0; n < 4; n++) {
        int r = wcol * 64 + 16 * n + (lane & 15);
        int cb = (ks * 64 + ((lane >> 4) << 4)) ^ ((r & 7) << 4);
        bfr[n] = *(const bf16x8*)(Bb + r * 128 + cb);
      }
#pragma unroll
      for (int m = 0; m < 4; m++)
#pragma unroll
        for (int n = 0; n < 4; n++)
          acc[m][n] = __builtin_amdgcn_mfma_f32_16x16x32_bf16(af[m], bfr[n], acc[m][n], 0, 0, 0);
    }
  }
  __syncthreads();   // all LDS reads done before reuse / exit

  if (OUTMODE == 0 || OUTMODE == 1) {
#pragma unroll
    for (int m = 0; m < 4; m++)
#pragma unroll
      for (int n = 0; n < 4; n++)
#pragma unroll
        for (int r = 0; r < 4; r++) {
          int row = row0 + wrow * 64 + 16 * m + ((lane >> 4) << 2) + r;
          int col = n0 + wcol * 64 + 16 * n + (lane & 15);
          if (OUTMODE == 0) outF[(long)row * ldo + col] = acc[m][n][r];
          else              outB[(long)row * ldo + col] = __float2bfloat16(acc[m][n][r]);
        }
  } else {
    // E1: gates -> LDS [128][128] f32, 16B XOR swizzle
#pragma unroll
    for (int m = 0; m < 4; m++)
#pragma unroll
      for (int n = 0; n < 4; n++)
#pragma unroll
        for (int r = 0; r < 4; r++) {
          int rr = wrow * 64 + 16 * m + ((lane >> 4) << 2) + r;
          int cc = wcol * 64 + 16 * n + (lane & 15);
          int byte = (rr << 9) + (((cc << 2)) ^ ((rr & 7) << 4));
          *(float*)(smem + byte) = acc[m][n][r];
        }
    __syncthreads();
    // E2: cell update; thread -> (j = tid&31, rows (tid>>5)+8i)
    int j = tid & 31;
    int rbase = tid >> 5;
#pragma unroll
    for (int i = 0; i < 16; i++) {
      int rr = rbase + 8 * i;
      int byte = (rr << 9) + ((j << 4) ^ ((rr & 7) << 4));
      f32x4 g4 = *(const f32x4*)(smem + byte);   // i, f, g, o
      int row = row0 + rr;
      int jj = ntile * 32 + j;
      float cold = cIn[(long)row * H_ + jj];
      float cn = fsig(g4[1]) * cold + fsig(g4[0]) * ftanh(g4[2]);
      float hn = fsig(g4[3]) * ftanh(cn);
      cOut[(long)row * H_ + jj] = cn;
      hOut[(long)row * H_ + jj] = __float2bfloat16(hn);
    }
  }
}

template <int OUTMODE>
__global__ __launch_bounds__(256) void gemm_generic(const bf16* A1, int lda1,
                                                    const bf16* W, int ldw, int K,
                                                    const float* bias,
                                                    float* outF, bf16* outB, int ldo) {
  __shared__ __align__(16) char smem[65536];
  int mtile = blockIdx.x & 31;
  int ntile = blockIdx.x >> 5;
  gemm_core<OUTMODE>(A1, lda1, A1 /*unused*/, W, ldw, K, bias, nullptr,
                     outF, outB, ldo, nullptr, nullptr, nullptr, mtile, ntile, smem);
}

__global__ __launch_bounds__(256) void lstm_diag(int d, char* __restrict__ ws) {
  __shared__ __align__(16) char smem[65536];
  int l0 = d > 63 ? d - 63 : 0;
  int l = l0 + blockIdx.y;
  int t = d - l;
  int mtile = blockIdx.x & 31;
  int ntile = blockIdx.x >> 5;
  int sp = (t & 1) ^ 1, op = t & 1;

  const bf16* wc = (const bf16*)(ws + OFF_WCOMB) + (long)l * G_ * 512;
  const bf16* A1; const bf16* A2 = nullptr; int K;
  const float* bias = nullptr; const float* acc2d = nullptr;
  if (l == 0) {
    A1 = h_ptr(ws, 0, sp); A2 = A1; K = 256;
    acc2d = (const float*)(ws + OFF_GX0);
  } else {
    A1 = h_ptr(ws, l - 1, op);
    A2 = (l == 4) ? ys_ptr(ws, t) : h_ptr(ws, l, sp);
    K = 512;
    bias = (const float*)(ws + OFF_BIAS) + l * G_;
  }
  const float* cIn = c_ptr(ws, l, sp);
  float* cOut = c_ptr(ws, l, op);
  bf16* hOut = (l == 4) ? ys_ptr(ws, t + 1) : h_ptr(ws, l, op);

  gemm_core<2>(A1, 256, A2, wc, 512, K, bias, acc2d,
               nullptr, nullptr, 0, cIn, cOut, hOut, mtile, ntile, smem);
}

__global__ __launch_bounds__(256) void proj_kernel(char* __restrict__ ws,
                                                   const float* __restrict__ ob,
                                                   float* __restrict__ out) {
  __shared__ __align__(16) char smem[49152];   // [96][256] bf16 swizzled
  int mtile = blockIdx.x;
  int t = blockIdx.y;
  const bf16* ys = ys_ptr(ws, t + 1);
  const char* obw = (const char*)(ws + OFF_OBW);
  int tid = threadIdx.x, lane = tid & 63, wv = tid >> 6;
#pragma unroll
  for (int i = 0; i < 12; i++) {
    int r = wv * 24 + i * 2 + (lane >> 5);
    int cb = ((lane & 31) << 4) ^ ((r & 7) << 4);
    gload16(obw + r * 512 + cb, smem + (wv * 24 + i * 2) * 512);
  }
  __syncthreads();
  f32x4 acc[2][6];
#pragma unroll
  for (int m = 0; m < 2; m++)
#pragma unroll
    for (int n = 0; n < 6; n++)
#pragma unroll
      for (int r = 0; r < 4; r++) acc[m][n][r] = 0.0f;
  const char* arow = (const char*)(ys + (long)(mtile * 128) * 256);
  for (int kk = 0; kk < 256; kk += 32) {
    bf16x8 af[2], bfr[6];
#pragma unroll
    for (int m = 0; m < 2; m++) {
      int r = wv * 32 + 16 * m + (lane & 15);
      af[m] = *(const bf16x8*)(arow + (long)r * 512 + kk * 2 + ((lane >> 4) << 4));
    }
#pragma unroll
    for (int n = 0; n < 6; n++) {
      int r = 16 * n + (lane & 15);
      int cb = (kk * 2 + ((lane >> 4) << 4)) ^ ((r & 7) << 4);
      bfr[n] = *(const bf16x8*)(smem + r * 512 + cb);
    }
#pragma unroll
    for (int m = 0; m < 2; m++)
#pragma unroll
      for (int n = 0; n < 6; n++)
        acc[m][n] = __builtin_amdgcn_mfma_f32_16x16x32_bf16(af[m], bfr[n], acc[m][n], 0, 0, 0);
  }
#pragma unroll
  for (int m = 0; m < 2; m++)
#pragma unroll
    for (int n = 0; n < 6; n++)
#pragma unroll
      for (int r = 0; r < 4; r++) {
        int row = mtile * 128 + wv * 32 + 16 * m + ((lane >> 4) << 2) + r;
        int o = 16 * n + (lane & 15);
        if (o < 88) {
          float v = acc[m][n][r] + ob[o];
          out[((long)row * T_ + t) * 88 + o] = fsig(v);
        }
      }
}

__global__ void prep_kernel(const float* __restrict__ x, const float* __restrict__ lw,
                            const float* __restrict__ wih, const float* __restrict__ whh,
                            const float* __restrict__ bih, const float* __restrict__ bhh,
                            const float* __restrict__ ow, char* __restrict__ ws) {
  bf16* xb = (bf16*)(ws + OFF_XB);
  bf16* lwb = (bf16*)(ws + OFF_LWB);
  bf16* wcomb = (bf16*)(ws + OFF_WCOMB);
  bf16* wih0r = (bf16*)(ws + OFF_WIH0R);
  bf16* obw = (bf16*)(ws + OFF_OBW);
  float* bias = (float*)(ws + OFF_BIAS);
  const int S0 = 524288, S1 = 32768, S2 = 2621440, S3 = 262144, S4 = 24576, S5 = 5120;
  const int total = S0 + S1 + S2 + S3 + S4 + S5;
  for (int i = blockIdx.x * blockDim.x + threadIdx.x; i < total; i += gridDim.x * blockDim.x) {
    int idx = i;
    if (idx < S0) { xb[idx] = __float2bfloat16(x[idx]); continue; }
    idx -= S0;
    if (idx < S1) { lwb[idx] = __float2bfloat16(lw[idx]); continue; }
    idx -= S1;
    if (idx < S2) {
      int l = idx >> 19;
      int rem = idx & 524287;
      int n = rem >> 9;
      int k = rem & 511;
      int row = (n & 3) * 256 + (n >> 2);
      float v;
      if (l == 0) v = (k < 256) ? whh[row * 256 + k] : 0.0f;
      else        v = (k < 256) ? wih[(l * 1024 + row) * 256 + k]
                                : whh[(l * 1024 + row) * 256 + (k - 256)];
      wcomb[idx] = __float2bfloat16(v); continue;
    }
    idx -= S2;
    if (idx < S3) {
      int n = idx >> 8, k = idx & 255;
      int row = (n & 3) * 256 + (n >> 2);
      wih0r[idx] = __float2bfloat16(wih[row * 256 + k]); continue;
    }
    idx -= S3;
    if (idx < S4) {
      int r = idx >> 8, k = idx & 255;
      obw[idx] = __float2bfloat16(r < 88 ? ow[r * 256 + k] : 0.0f); continue;
    }
    idx -= S4;
    {
      int l = idx >> 10, n = idx & 1023;
      int row = (n & 3) * 256 + (n >> 2);
      bias[idx] = bih[l * 1024 + row] + bhh[l * 1024 + row];
    }
  }
}

extern "C" void kernel_launch(void* const* d_in, const int* in_sizes, int n_in,
                              void* d_out, int out_size, void* d_ws, size_t ws_size,
                              hipStream_t stream) {
  const float* x   = (const float*)d_in[0];
  const float* lw  = (const float*)d_in[1];
  const float* lb  = (const float*)d_in[2];
  const float* wih = (const float*)d_in[3];
  const float* whh = (const float*)d_in[4];
  const float* bih = (const float*)d_in[5];
  const float* bhh = (const float*)d_in[6];
  const float* ow  = (const float*)d_in[7];
  const float* ob  = (const float*)d_in[8];
  char* ws = (char*)d_ws;
  float* out = (float*)d_out;

  if (ws_size < TOTAL_WS) return;  // workspace too small: fail cleanly (signals sizing issue)

  hipMemsetAsync(ws + OFF_H1, 0, ZERO_BYTES, stream);
  prep_kernel<<<2048, 256, 0, stream>>>(x, lw, wih, whh, bih, bhh, ow, ws);

  // xp = bf16(x @ linear_w^T + linear_b)   [4096,256]
  gemm_generic<1><<<dim3(64), 256, 0, stream>>>(
      (const bf16*)(ws + OFF_XB), 128, (const bf16*)(ws + OFF_LWB), 128, 128,
      lb, nullptr, (bf16*)(ws + OFF_XP), 256);

  // gx0 = xp @ w_ih0r^T + (b_ih0 + b_hh0)  [4096,1024] f32 (gate-interleaved)
  gemm_generic<0><<<dim3(256), 256, 0, stream>>>(
      (const bf16*)(ws + OFF_XP), 256, (const bf16*)(ws + OFF_WIH0R), 256, 256,
      (const float*)(ws + OFF_BIAS), (float*)(ws + OFF_GX0), nullptr, 1024);

  // wavefront over diagonals d = t + l
  for (int d = 0; d < 68; ++d) {
    int lo = d > 63 ? d - 63 : 0;
    int hi = d < 4 ? d : 4;
    int nc = hi - lo + 1;
    lstm_diag<<<dim3(256, nc), 256, 0, stream>>>(d, ws);
  }

  // out = sigmoid(ys @ out_w^T + out_b)  [4096,64,88] f32
  proj_kernel<<<dim3(32, 64), 256, 0, stream>>>(ws, ob, out);
}